// Round 1
// baseline (673.974 us; speedup 1.0000x reference)
//
#include <hip/hip_runtime.h>
#include <stdint.h>

// ---------------------------------------------------------------------------
// SNN EMNIST forward: T=10, B=4096, IN=784, HID=256, NCLS=47
// Pipeline: spikegen (threefry) -> gemm1 (spikes@W1) -> LIF scan -> readout
// ---------------------------------------------------------------------------

#define T_STEPS 10
#define BATCH   4096
#define IN_DIM  784
#define HID     256
#define NCLS    47
#define NROWS   (T_STEPS * BATCH)        // 40960
#define KWORDS  25                       // ceil(784/32)

// d_ws layout (bytes):
//   [0, 41943040)          I_all  : float [40960][256]
//   [41943040, 46039040)   spk    : u32   [25][10][4096]   (bit kk of word = k)
//   [46039040, 50233344)   g      : float [4096][256]
#define WS_IALL_OFF 0u
#define WS_SPK_OFF  41943040u
#define WS_G_OFF    46039040u

__device__ __forceinline__ uint32_t rotl32(uint32_t x, int r) {
    return (x << r) | (x >> (32 - r));
}

// JAX threefry2x32, key = (0, 42)  [jax.random.key(42)].
// Partitionable scheme: x0 = hi(index) = 0, x1 = lo(index); output = o0 ^ o1.
__device__ __forceinline__ uint32_t tf_hash(uint32_t lo) {
    const uint32_t ks0 = 0u;
    const uint32_t ks1 = 42u;
    const uint32_t ks2 = 0x1BD11BDAu ^ 0u ^ 42u;
    uint32_t x0 = 0u + ks0;
    uint32_t x1 = lo + ks1;
#define TF_RND(r) { x0 += x1; x1 = rotl32(x1, r); x1 ^= x0; }
    TF_RND(13) TF_RND(15) TF_RND(26) TF_RND(6)
    x0 += ks1; x1 += ks2 + 1u;
    TF_RND(17) TF_RND(29) TF_RND(16) TF_RND(24)
    x0 += ks2; x1 += ks0 + 2u;
    TF_RND(13) TF_RND(15) TF_RND(26) TF_RND(6)
    x0 += ks0; x1 += ks1 + 3u;
    TF_RND(17) TF_RND(29) TF_RND(16) TF_RND(24)
    x0 += ks1; x1 += ks2 + 4u;
    TF_RND(13) TF_RND(15) TF_RND(26) TF_RND(6)
    x0 += ks2; x1 += ks0 + 5u;
#undef TF_RND
    return x0 ^ x1;
}

// ---------------------------------------------------------------------------
// Kernel A: spike generation.
// thread = (kw, b): kw = tid>>12 (word index 0..24), b = tid&4095.
// For each k in word, each t: spike = float(bits>>9) < x[b,k]*2^23  (exact).
// Output layout: spk[(kw*10 + t)*4096 + b]  -> coalesced writes over b.
// ---------------------------------------------------------------------------
__global__ __launch_bounds__(256) void spikegen_k(
        const float* __restrict__ x, uint32_t* __restrict__ spk) {
    int tid = blockIdx.x * 256 + threadIdx.x;
    if (tid >= KWORDS * BATCH) return;
    int kw = tid >> 12;          // 0..24
    int b  = tid & 4095;
    int kbase = kw << 5;
    int nk = (kw == 24) ? 16 : 32;

    uint32_t words[T_STEPS];
#pragma unroll
    for (int t = 0; t < T_STEPS; ++t) words[t] = 0u;

    for (int kk = 0; kk < nk; ++kk) {
        int k = kbase + kk;
        float Xv = x[b * IN_DIM + k] * 8388608.0f;     // p * 2^23, exact
        uint32_t i0 = (uint32_t)(b * IN_DIM + k);
#pragma unroll
        for (int t = 0; t < T_STEPS; ++t) {
            uint32_t w = tf_hash(i0 + (uint32_t)t * (uint32_t)(BATCH * IN_DIM));
            float mf = (float)(w >> 9);                // exact, < 2^23
            if (mf < Xv) words[t] |= (1u << kk);
        }
    }
#pragma unroll
    for (int t = 0; t < T_STEPS; ++t)
        spk[(kw * T_STEPS + t) * BATCH + b] = words[t];
}

// ---------------------------------------------------------------------------
// Kernel B: I_all[m][h] = sum_k s[m][k]*W1[k][h] + b1[h],  m = t*4096+b.
// Block: 64 rows x 256 cols. 256 threads: tx=tid&63 (4 cols), ty=tid>>6
// (rows ty+4j). Spike words are wave-uniform (wave = fixed ty) -> scalar
// branch skips zero contributions entirely (adds only, s==1 exactly).
// ---------------------------------------------------------------------------
__global__ __launch_bounds__(256, 4) void gemm1_k(
        const float* __restrict__ W1, const float* __restrict__ b1,
        const uint32_t* __restrict__ spk, float* __restrict__ I_all) {
    __shared__ float w1t[32 * 256];     // 32 KB: one k-chunk of W1
    __shared__ uint32_t swl[64];        // spike word per block row

    const int tid = threadIdx.x;
    const int tx = tid & 63;
    const int ty = tid >> 6;
    const int h0 = tx << 2;
    const int m0 = blockIdx.x << 6;                // global row base = t*4096+b0
    const int t  = blockIdx.x >> 6;                // timestep of this block
    const int b0 = (blockIdx.x & 63) << 6;

    float acc[16][4];
#pragma unroll
    for (int j = 0; j < 16; ++j) {
        acc[j][0] = 0.f; acc[j][1] = 0.f; acc[j][2] = 0.f; acc[j][3] = 0.f;
    }

    for (int chunk = 0; chunk < KWORDS; ++chunk) {
        const int kn = (chunk == 24) ? 16 : 32;
        __syncthreads();
        // stage W1 rows [chunk*32, chunk*32+kn) -> LDS (coalesced float4)
        for (int e = tid << 2; e < (kn << 8); e += 1024) {
            *(float4*)&w1t[e] = *(const float4*)&W1[(chunk << 13) + e];
        }
        if (tid < 64)
            swl[tid] = spk[(chunk * T_STEPS + t) * BATCH + b0 + tid];
        __syncthreads();

        uint32_t wu[16];
#pragma unroll
        for (int j = 0; j < 16; ++j)
            wu[j] = (uint32_t)__builtin_amdgcn_readfirstlane(
                        (int)swl[ty + (j << 2)]);

#pragma unroll 8
        for (int kk = 0; kk < 32; ++kk) {
            // bits kk>=kn are never set, so stale LDS rows are never added
            float4 w = *(float4*)&w1t[(kk << 8) + h0];
#pragma unroll
            for (int j = 0; j < 16; ++j) {
                if (wu[j] & (1u << kk)) {   // wave-uniform -> scalar branch
                    acc[j][0] += w.x; acc[j][1] += w.y;
                    acc[j][2] += w.z; acc[j][3] += w.w;
                }
            }
        }
    }

    float4 bb = *(const float4*)&b1[h0];
#pragma unroll
    for (int j = 0; j < 16; ++j) {
        int row = m0 + ty + (j << 2);
        float4 o;
        o.x = acc[j][0] + bb.x; o.y = acc[j][1] + bb.y;
        o.z = acc[j][2] + bb.z; o.w = acc[j][3] + bb.w;
        *(float4*)&I_all[(row << 8) + h0] = o;
    }
}

// ---------------------------------------------------------------------------
// Kernel C: LIF scan over t per (b,h); emits g[b,h] = sum_t 2^(t-10)*spk_t.
// Reproduces reference f32 op sequence: v += (I-v)*0.5; spk=(v>=1); reset.
// ---------------------------------------------------------------------------
__global__ __launch_bounds__(256) void scan_k(
        const float* __restrict__ I_all, float* __restrict__ g) {
    int b = blockIdx.x;
    int h = threadIdx.x;
    const float* p = I_all + ((size_t)b << 8) + h;
    float v = 0.f, ga = 0.f, wt = 0.0009765625f;   // 2^-10
#pragma unroll
    for (int t = 0; t < T_STEPS; ++t) {
        float I = p[(size_t)t * BATCH * HID];
        v = v + (I - v) * 0.5f;
        if (v >= 1.0f) { ga += wt; v = 0.f; }
        wt += wt;
    }
    g[(b << 8) + h] = ga;
}

// ---------------------------------------------------------------------------
// Kernel D: out[b][c] = sum_h g[b][h]*Wr[h][c] + br[c]*(1 - 2^-10).
// Block: 4 rows x 64 lanes (c<47 active); g rows staged in LDS (broadcast).
// ---------------------------------------------------------------------------
__global__ __launch_bounds__(256) void out_k(
        const float* __restrict__ g, const float* __restrict__ Wr,
        const float* __restrict__ br, float* __restrict__ out) {
    __shared__ float gl[4 * 256];
    int tid = threadIdx.x;
    int b0 = blockIdx.x << 2;
    *(float4*)&gl[tid << 2] = *(const float4*)&g[(b0 << 8) + (tid << 2)];
    __syncthreads();
    int row = tid >> 6;
    int c = tid & 63;
    if (c >= NCLS) return;
    const float* grow = &gl[row << 8];
    float acc = 0.f;
#pragma unroll 4
    for (int h = 0; h < HID; ++h)
        acc = fmaf(grow[h], Wr[h * NCLS + c], acc);
    out[(b0 + row) * NCLS + c] = acc + br[c] * 0.9990234375f;
}

extern "C" void kernel_launch(void* const* d_in, const int* in_sizes, int n_in,
                              void* d_out, int out_size, void* d_ws, size_t ws_size,
                              hipStream_t stream) {
    const float* x  = (const float*)d_in[0];
    const float* W1 = (const float*)d_in[1];
    const float* b1 = (const float*)d_in[2];
    const float* Wr = (const float*)d_in[3];
    const float* br = (const float*)d_in[4];
    float* out = (float*)d_out;

    float*    I_all = (float*)   ((char*)d_ws + WS_IALL_OFF);
    uint32_t* spk   = (uint32_t*)((char*)d_ws + WS_SPK_OFF);
    float*    g     = (float*)   ((char*)d_ws + WS_G_OFF);

    spikegen_k<<<(KWORDS * BATCH) / 256, 256, 0, stream>>>(x, spk);
    gemm1_k<<<NROWS / 64, 256, 0, stream>>>(W1, b1, spk, I_all);
    scan_k<<<BATCH, 256, 0, stream>>>(I_all, g);
    out_k<<<BATCH / 4, 256, 0, stream>>>(g, Wr, br, out);
}

// Round 3
// 247.101 us; speedup vs baseline: 2.7275x; 2.7275x over previous
//
#include <hip/hip_runtime.h>
#include <stdint.h>

// ---------------------------------------------------------------------------
// SNN EMNIST forward: T=10, B=4096, IN=784, HID=256, NCLS=47
// spikegen (threefry) -> split W1 (EXACT 3-way bf16) -> MFMA gemm -> scan -> out
// ---------------------------------------------------------------------------

#define T_STEPS 10
#define BATCH   4096
#define IN_DIM  784
#define HID     256
#define NCLS    47
#define NROWS   (T_STEPS * BATCH)        // 40960
#define KWORDS  25                       // ceil(784/32)
#define KPAD    800                      // 25*32

// d_ws layout (bytes):
//   [0, 41943040)          I_all  : float [40960][256]
//   [41943040, 46039040)   spk    : u32   [25][10][4096]
//   [46039040, 50233344)   g      : float [4096][256]
//   W1{hi,mid,lo}T (bf16 [256][800], 409600 B each = 1228800 B total)
//   OVERLAP the g region (4 MB): dead once gemm finishes; scan_k overwrites.
#define WS_IALL_OFF 0u
#define WS_SPK_OFF  41943040u
#define WS_G_OFF    46039040u
#define WS_W1HI_OFF WS_G_OFF
#define WS_W1MD_OFF (WS_G_OFF + 409600u)
#define WS_W1LO_OFF (WS_G_OFF + 819200u)

typedef __attribute__((ext_vector_type(8))) short    bf16x8;
typedef __attribute__((ext_vector_type(4))) float    f32x4;
typedef __attribute__((ext_vector_type(4))) uint32_t u32x4;

__device__ __forceinline__ uint32_t rotl32(uint32_t x, int r) {
    return (x << r) | (x >> (32 - r));
}

// JAX threefry2x32, key=(0,42), partitionable scheme: out = o0^o1, x0=0, x1=i.
__device__ __forceinline__ uint32_t tf_hash(uint32_t lo) {
    const uint32_t ks0 = 0u;
    const uint32_t ks1 = 42u;
    const uint32_t ks2 = 0x1BD11BDAu ^ 0u ^ 42u;
    uint32_t x0 = 0u + ks0;
    uint32_t x1 = lo + ks1;
#define TF_RND(r) { x0 += x1; x1 = rotl32(x1, r); x1 ^= x0; }
    TF_RND(13) TF_RND(15) TF_RND(26) TF_RND(6)
    x0 += ks1; x1 += ks2 + 1u;
    TF_RND(17) TF_RND(29) TF_RND(16) TF_RND(24)
    x0 += ks2; x1 += ks0 + 2u;
    TF_RND(13) TF_RND(15) TF_RND(26) TF_RND(6)
    x0 += ks0; x1 += ks1 + 3u;
    TF_RND(17) TF_RND(29) TF_RND(16) TF_RND(24)
    x0 += ks1; x1 += ks2 + 4u;
    TF_RND(13) TF_RND(15) TF_RND(26) TF_RND(6)
    x0 += ks2; x1 += ks0 + 5u;
#undef TF_RND
    return x0 ^ x1;
}

// ---------------------------------------------------------------------------
// Kernel A: spike generation -> bit-packed words spk[(kw*10+t)*4096 + b].
// ---------------------------------------------------------------------------
__global__ __launch_bounds__(256) void spikegen_k(
        const float* __restrict__ x, uint32_t* __restrict__ spk) {
    int tid = blockIdx.x * 256 + threadIdx.x;
    if (tid >= KWORDS * BATCH) return;
    int kw = tid >> 12;
    int b  = tid & 4095;
    int kbase = kw << 5;
    int nk = (kw == 24) ? 16 : 32;

    uint32_t words[T_STEPS];
#pragma unroll
    for (int t = 0; t < T_STEPS; ++t) words[t] = 0u;

    for (int kk = 0; kk < nk; ++kk) {
        int k = kbase + kk;
        float Xv = x[b * IN_DIM + k] * 8388608.0f;     // p * 2^23, exact
        uint32_t i0 = (uint32_t)(b * IN_DIM + k);
#pragma unroll
        for (int t = 0; t < T_STEPS; ++t) {
            uint32_t w = tf_hash(i0 + (uint32_t)t * (uint32_t)(BATCH * IN_DIM));
            float mf = (float)(w >> 9);                // exact, < 2^23
            if (mf < Xv) words[t] |= (1u << kk);
        }
    }
#pragma unroll
    for (int t = 0; t < T_STEPS; ++t)
        spk[(kw * T_STEPS + t) * BATCH + b] = words[t];
}

// ---------------------------------------------------------------------------
// Kernel B0: split W1 (f32 [784][256]) into transposed bf16 hi/mid/lo
// [256][800]. EXACT: hi+mid+lo == w bitwise (r2 has <=7 significant bits
// after two Sterbenz-exact subtractions -> lo stores it exactly).
// ---------------------------------------------------------------------------
__global__ __launch_bounds__(256) void splitk_k(
        const float* __restrict__ W1, ushort* __restrict__ hiT,
        ushort* __restrict__ midT, ushort* __restrict__ loT) {
    int n = blockIdx.x;                  // 0..255
    for (int k = threadIdx.x; k < KPAD; k += 256) {
        float w = (k < IN_DIM) ? W1[k * HID + n] : 0.0f;
        uint32_t u = __float_as_uint(w);
        uint32_t hb = (u + 0x7FFFu + ((u >> 16) & 1u)) >> 16;    // RNE to bf16
        float hf = __uint_as_float(hb << 16);
        float r1 = w - hf;                                       // exact
        uint32_t u1 = __float_as_uint(r1);
        uint32_t mb = (u1 + 0x7FFFu + ((u1 >> 16) & 1u)) >> 16;  // RNE
        float mf2 = __uint_as_float(mb << 16);
        float r2 = r1 - mf2;                                     // exact
        uint32_t u2 = __float_as_uint(r2);
        uint32_t lb = (u2 + 0x7FFFu + ((u2 >> 16) & 1u)) >> 16;  // exact fit
        hiT [n * KPAD + k] = (ushort)hb;
        midT[n * KPAD + k] = (ushort)mb;
        loT [n * KPAD + k] = (ushort)lb;
    }
}

// ---------------------------------------------------------------------------
// Kernel B: I_all = spikes @ W1 + b1 via bf16 MFMA (hi+mid+lo exact split).
// Block: 64 rows (one t, 64 b) x 256 cols, 4 waves; wave = 64 rows x 64 cols
// = 4x4 tiles of 16x16x32. K-loop over 25 spike words (K=32 each).
// LDS: A 4KB (bit-expanded spikes) + Bhi/Bmid/Blo 16KB each = 52KB, all in
// XOR-swizzled 16B quarters so every ds_read_b128 is <=2-way (free).
// B staged with global_load_lds width=16 (lane i -> ldsbase + i*16).
// Frag layouts (verified m89/m120): A[m=lane&15][k=(lane>>4)*8+j],
// B[k=(lane>>4)*8+j][n=lane&15], C/D col=lane&15,row=(lane>>4)*4+reg.
// ---------------------------------------------------------------------------
#define LDS_A  0
#define LDS_BH 4096
#define LDS_BM 20480
#define LDS_BL 36864

__global__ __launch_bounds__(256, 3) void gemm_mfma_k(
        const ushort* __restrict__ hiT, const ushort* __restrict__ midT,
        const ushort* __restrict__ loT, const float* __restrict__ b1,
        const uint32_t* __restrict__ spk, float* __restrict__ I_all) {
    __shared__ __align__(16) char lds[53248];

    const int tid = threadIdx.x;
    const int l   = tid & 63;
    const int wv  = tid >> 6;
    const int t   = blockIdx.x >> 6;
    const int b0  = (blockIdx.x & 63) << 6;
    const int m0  = blockIdx.x << 6;

    f32x4 acc[4][4] = {};

    // fragment read addressing (shared swizzle sig for A and B)
    const int q   = l >> 4;
    const int sig = q ^ (l & 3) ^ ((l >> 2) & 3);
    const int a_base = LDS_A + ((l & 15) << 6) + (sig << 4);
    const int b_off  = (((wv << 6) + (l & 15)) << 6) + (sig << 4);

    // A-expansion thread mapping: row er, byte-group eq
    const int er = tid >> 2;
    const int eq = tid & 3;
    const int ea = LDS_A + (er << 6) + ((eq ^ (er & 3) ^ ((er >> 2) & 3)) << 4);
    const uint32_t* wptr = spk + (size_t)t * BATCH + b0 + er;

    for (int kw = 0; kw < KWORDS; ++kw) {
        __syncthreads();   // previous compute done with LDS

        // --- stage Bhi/Bmid/Blo chunk (k in [kw*32,kw*32+32), all 256 n) ---
#pragma unroll
        for (int i = 0; i < 4; ++i) {
            int s  = (wv << 8) + (i << 6) + l;          // slot 0..1023
            int n  = s >> 2;
            int qs = s & 3;
            int qd = qs ^ (n & 3) ^ ((n >> 2) & 3);     // swizzled data quarter
            size_t gb = (size_t)n * (KPAD * 2) + ((size_t)kw << 6) + ((size_t)qd << 4);
            int ldst = ((wv << 8) + (i << 6)) << 4;
            __builtin_amdgcn_global_load_lds(
                (const __attribute__((address_space(1))) void*)((const char*)hiT + gb),
                (__attribute__((address_space(3))) void*)(lds + LDS_BH + ldst),
                16, 0, 0);
            __builtin_amdgcn_global_load_lds(
                (const __attribute__((address_space(1))) void*)((const char*)midT + gb),
                (__attribute__((address_space(3))) void*)(lds + LDS_BM + ldst),
                16, 0, 0);
            __builtin_amdgcn_global_load_lds(
                (const __attribute__((address_space(1))) void*)((const char*)loT + gb),
                (__attribute__((address_space(3))) void*)(lds + LDS_BL + ldst),
                16, 0, 0);
        }

        // --- expand spike bits -> bf16 A tile (64 rows x 32 k) ---
        {
            uint32_t w = wptr[(size_t)kw * NROWS];
            uint32_t byte = (w >> (eq << 3)) & 0xFFu;
            u32x4 v;
            v.x = ((byte &   1u) ? 0x3F80u : 0u) | ((byte &   2u) ? 0x3F800000u : 0u);
            v.y = ((byte &   4u) ? 0x3F80u : 0u) | ((byte &   8u) ? 0x3F800000u : 0u);
            v.z = ((byte &  16u) ? 0x3F80u : 0u) | ((byte &  32u) ? 0x3F800000u : 0u);
            v.w = ((byte &  64u) ? 0x3F80u : 0u) | ((byte & 128u) ? 0x3F800000u : 0u);
            *(u32x4*)(lds + ea) = v;
        }

        __syncthreads();   // A visible + global_load_lds drained

        // --- compute: 4 mtiles x 4 ntiles x (hi,mid,lo) = 48 MFMA ---
        bf16x8 af[4];
#pragma unroll
        for (int mt = 0; mt < 4; ++mt)
            af[mt] = *(const bf16x8*)(lds + a_base + (mt << 10));
#pragma unroll
        for (int nt = 0; nt < 4; ++nt) {
            bf16x8 bh = *(const bf16x8*)(lds + LDS_BH + b_off + (nt << 10));
            bf16x8 bm = *(const bf16x8*)(lds + LDS_BM + b_off + (nt << 10));
            bf16x8 bl = *(const bf16x8*)(lds + LDS_BL + b_off + (nt << 10));
#pragma unroll
            for (int mt = 0; mt < 4; ++mt) {
                acc[mt][nt] = __builtin_amdgcn_mfma_f32_16x16x32_bf16(af[mt], bh, acc[mt][nt], 0, 0, 0);
                acc[mt][nt] = __builtin_amdgcn_mfma_f32_16x16x32_bf16(af[mt], bm, acc[mt][nt], 0, 0, 0);
                acc[mt][nt] = __builtin_amdgcn_mfma_f32_16x16x32_bf16(af[mt], bl, acc[mt][nt], 0, 0, 0);
            }
        }
    }

    // --- epilogue: acc -> I_all (+ b1) ---
    const int c0 = l & 15;
    float b1v[4];
#pragma unroll
    for (int nt = 0; nt < 4; ++nt)
        b1v[nt] = b1[(wv << 6) + (nt << 4) + c0];
#pragma unroll
    for (int mt = 0; mt < 4; ++mt) {
#pragma unroll
        for (int nt = 0; nt < 4; ++nt) {
            int col = (wv << 6) + (nt << 4) + c0;
#pragma unroll
            for (int r = 0; r < 4; ++r) {
                int row = m0 + (mt << 4) + (q << 2) + r;
                I_all[(size_t)row * HID + col] = acc[mt][nt][r] + b1v[nt];
            }
        }
    }
}

// ---------------------------------------------------------------------------
// Kernel C: LIF scan over t per (b,h); g[b,h] = sum_t 2^(t-10)*spk_t.
// ---------------------------------------------------------------------------
__global__ __launch_bounds__(256) void scan_k(
        const float* __restrict__ I_all, float* __restrict__ g) {
    int b = blockIdx.x;
    int h = threadIdx.x;
    const float* p = I_all + ((size_t)b << 8) + h;
    float v = 0.f, ga = 0.f, wt = 0.0009765625f;   // 2^-10
#pragma unroll
    for (int t = 0; t < T_STEPS; ++t) {
        float I = p[(size_t)t * BATCH * HID];
        v = v + (I - v) * 0.5f;
        if (v >= 1.0f) { ga += wt; v = 0.f; }
        wt += wt;
    }
    g[(b << 8) + h] = ga;
}

// ---------------------------------------------------------------------------
// Kernel D: out[b][c] = sum_h g[b][h]*Wr[h][c] + br[c]*(1 - 2^-10).
// ---------------------------------------------------------------------------
__global__ __launch_bounds__(256) void out_k(
        const float* __restrict__ g, const float* __restrict__ Wr,
        const float* __restrict__ br, float* __restrict__ out) {
    __shared__ float gl[4 * 256];
    int tid = threadIdx.x;
    int b0 = blockIdx.x << 2;
    *(float4*)&gl[tid << 2] = *(const float4*)&g[(b0 << 8) + (tid << 2)];
    __syncthreads();
    int row = tid >> 6;
    int c = tid & 63;
    if (c >= NCLS) return;
    const float* grow = &gl[row << 8];
    float acc = 0.f;
#pragma unroll 4
    for (int h = 0; h < HID; ++h)
        acc = fmaf(grow[h], Wr[h * NCLS + c], acc);
    out[(b0 + row) * NCLS + c] = acc + br[c] * 0.9990234375f;
}

extern "C" void kernel_launch(void* const* d_in, const int* in_sizes, int n_in,
                              void* d_out, int out_size, void* d_ws, size_t ws_size,
                              hipStream_t stream) {
    const float* x  = (const float*)d_in[0];
    const float* W1 = (const float*)d_in[1];
    const float* b1 = (const float*)d_in[2];
    const float* Wr = (const float*)d_in[3];
    const float* br = (const float*)d_in[4];
    float* out = (float*)d_out;

    float*    I_all = (float*)   ((char*)d_ws + WS_IALL_OFF);
    uint32_t* spk   = (uint32_t*)((char*)d_ws + WS_SPK_OFF);
    float*    g     = (float*)   ((char*)d_ws + WS_G_OFF);
    ushort*   w1hi  = (ushort*)  ((char*)d_ws + WS_W1HI_OFF);
    ushort*   w1md  = (ushort*)  ((char*)d_ws + WS_W1MD_OFF);
    ushort*   w1lo  = (ushort*)  ((char*)d_ws + WS_W1LO_OFF);

    splitk_k<<<HID, 256, 0, stream>>>(W1, w1hi, w1md, w1lo);
    spikegen_k<<<(KWORDS * BATCH) / 256, 256, 0, stream>>>(x, spk);
    gemm_mfma_k<<<NROWS / 64, 256, 0, stream>>>(w1hi, w1md, w1lo, b1, spk, I_all);
    scan_k<<<BATCH, 256, 0, stream>>>(I_all, g);
    out_k<<<BATCH / 4, 256, 0, stream>>>(g, Wr, br, out);
}

// Round 4
// 234.615 us; speedup vs baseline: 2.8727x; 1.0532x over previous
//
#include <hip/hip_runtime.h>
#include <stdint.h>

// ---------------------------------------------------------------------------
// SNN EMNIST forward: T=10, B=4096, IN=784, HID=256, NCLS=47
// spikegen (threefry) -> split W1 (EXACT 3-way bf16) -> MFMA gemm -> scan -> out
// ---------------------------------------------------------------------------

#define T_STEPS 10
#define BATCH   4096
#define IN_DIM  784
#define HID     256
#define NCLS    47
#define NROWS   (T_STEPS * BATCH)        // 40960
#define KWORDS  25                       // ceil(784/32)
#define KPAD    800                      // 25*32

// d_ws layout (bytes):
//   [0, 41943040)          I_all  : float [40960][256]
//   [41943040, 46039040)   spk    : u32   [25][10][4096]
//   [46039040, 50233344)   g      : float [4096][256]
//   W1{hi,mid,lo}T (bf16 [256][800], 409600 B each) OVERLAP the g region:
//   dead once gemm finishes; scan_k overwrites with g.
#define WS_IALL_OFF 0u
#define WS_SPK_OFF  41943040u
#define WS_G_OFF    46039040u
#define WS_W1HI_OFF WS_G_OFF
#define WS_W1MD_OFF (WS_G_OFF + 409600u)
#define WS_W1LO_OFF (WS_G_OFF + 819200u)

typedef __attribute__((ext_vector_type(8))) short    bf16x8;
typedef __attribute__((ext_vector_type(4))) float    f32x4;
typedef __attribute__((ext_vector_type(4))) uint32_t u32x4;

__device__ __forceinline__ uint32_t rotl32(uint32_t x, int r) {
    return (x << r) | (x >> (32 - r));
}

// JAX threefry2x32, key=(0,42), partitionable scheme: out = o0^o1, x0=0, x1=i.
__device__ __forceinline__ uint32_t tf_hash(uint32_t lo) {
    const uint32_t ks0 = 0u;
    const uint32_t ks1 = 42u;
    const uint32_t ks2 = 0x1BD11BDAu ^ 0u ^ 42u;
    uint32_t x0 = 0u + ks0;
    uint32_t x1 = lo + ks1;
#define TF_RND(r) { x0 += x1; x1 = rotl32(x1, r); x1 ^= x0; }
    TF_RND(13) TF_RND(15) TF_RND(26) TF_RND(6)
    x0 += ks1; x1 += ks2 + 1u;
    TF_RND(17) TF_RND(29) TF_RND(16) TF_RND(24)
    x0 += ks2; x1 += ks0 + 2u;
    TF_RND(13) TF_RND(15) TF_RND(26) TF_RND(6)
    x0 += ks0; x1 += ks1 + 3u;
    TF_RND(17) TF_RND(29) TF_RND(16) TF_RND(24)
    x0 += ks1; x1 += ks2 + 4u;
    TF_RND(13) TF_RND(15) TF_RND(26) TF_RND(6)
    x0 += ks2; x1 += ks0 + 5u;
#undef TF_RND
    return x0 ^ x1;
}

// ---------------------------------------------------------------------------
// Kernel A: spike generation -> bit-packed words spk[(kw*10+t)*4096 + b].
// Thread = (kw, tg, b): tg covers t = {2tg, 2tg+1}. Grid = 25*5*16 = 2000
// blocks (31 waves/CU in flight vs 6.25 before) so the 20-round threefry
// dependency chains are latency-hidden. x loaded as float4 (16B-aligned),
// each load amortized over 2 hashes; kw==24 upper half skipped (bits 16..31
// stay 0, k>=784 does not exist).
// ---------------------------------------------------------------------------
__global__ __launch_bounds__(256) void spikegen_k(
        const float* __restrict__ x, uint32_t* __restrict__ spk) {
    const int bid = blockIdx.x;          // (kw*5 + tg)*16 + bblk
    const int kw  = bid / 80;
    const int rem = bid - kw * 80;
    const int tg  = rem >> 4;
    const int b   = ((rem & 15) << 8) + threadIdx.x;
    const int t0  = tg << 1;
    const int kbase = kw << 5;

    const uint32_t tstep = (uint32_t)(BATCH * IN_DIM);
    const uint32_t ibase0 = (uint32_t)(b * IN_DIM + kbase) + (uint32_t)t0 * tstep;

    uint32_t w0 = 0u, w1 = 0u;
    const int ng = (kw == 24) ? 4 : 8;   // float4 groups (wave-uniform branch)

    for (int g4 = 0; g4 < ng; ++g4) {
        float4 xv = *(const float4*)&x[b * IN_DIM + kbase + (g4 << 2)];
        float Xs[4] = {xv.x * 8388608.0f, xv.y * 8388608.0f,
                       xv.z * 8388608.0f, xv.w * 8388608.0f};
#pragma unroll
        for (int j = 0; j < 4; ++j) {
            int kk = (g4 << 2) + j;
            uint32_t i0 = ibase0 + (uint32_t)kk;
            uint32_t h0 = tf_hash(i0);
            uint32_t h1 = tf_hash(i0 + tstep);
            if ((float)(h0 >> 9) < Xs[j]) w0 |= (1u << kk);
            if ((float)(h1 >> 9) < Xs[j]) w1 |= (1u << kk);
        }
    }
    spk[(kw * T_STEPS + t0    ) * BATCH + b] = w0;
    spk[(kw * T_STEPS + t0 + 1) * BATCH + b] = w1;
}

// ---------------------------------------------------------------------------
// Kernel B0: split W1 (f32 [784][256]) into transposed bf16 hi/mid/lo
// [256][800]. EXACT: hi+mid+lo == w bitwise (r2 has <=7 significant bits
// after two Sterbenz-exact subtractions -> lo stores it exactly).
// ---------------------------------------------------------------------------
__global__ __launch_bounds__(256) void splitk_k(
        const float* __restrict__ W1, ushort* __restrict__ hiT,
        ushort* __restrict__ midT, ushort* __restrict__ loT) {
    int n = blockIdx.x;                  // 0..255
    for (int k = threadIdx.x; k < KPAD; k += 256) {
        float w = (k < IN_DIM) ? W1[k * HID + n] : 0.0f;
        uint32_t u = __float_as_uint(w);
        uint32_t hb = (u + 0x7FFFu + ((u >> 16) & 1u)) >> 16;    // RNE to bf16
        float hf = __uint_as_float(hb << 16);
        float r1 = w - hf;                                       // exact
        uint32_t u1 = __float_as_uint(r1);
        uint32_t mb = (u1 + 0x7FFFu + ((u1 >> 16) & 1u)) >> 16;  // RNE
        float mf2 = __uint_as_float(mb << 16);
        float r2 = r1 - mf2;                                     // exact
        uint32_t u2 = __float_as_uint(r2);
        uint32_t lb = (u2 + 0x7FFFu + ((u2 >> 16) & 1u)) >> 16;  // exact fit
        hiT [n * KPAD + k] = (ushort)hb;
        midT[n * KPAD + k] = (ushort)mb;
        loT [n * KPAD + k] = (ushort)lb;
    }
}

// ---------------------------------------------------------------------------
// Kernel B: I_all = spikes @ W1 + b1 via bf16 MFMA (hi+mid+lo exact split).
// Block: 64 rows (one t, 64 b) x 256 cols, 4 waves; wave = 64 rows x 64 cols
// = 4x4 tiles of 16x16x32. K-loop over 25 spike words (K=32 each).
// LDS: A 4KB (bit-expanded spikes) + Bhi/Bmid/Blo 16KB each = 52KB, all in
// XOR-swizzled 16B quarters so every ds_read_b128 is <=2-way (free).
// B staged with global_load_lds width=16 (lane i -> ldsbase + i*16).
// Frag layouts (verified m89/m120): A[m=lane&15][k=(lane>>4)*8+j],
// B[k=(lane>>4)*8+j][n=lane&15], C/D col=lane&15,row=(lane>>4)*4+reg.
// ---------------------------------------------------------------------------
#define LDS_A  0
#define LDS_BH 4096
#define LDS_BM 20480
#define LDS_BL 36864

__global__ __launch_bounds__(256, 3) void gemm_mfma_k(
        const ushort* __restrict__ hiT, const ushort* __restrict__ midT,
        const ushort* __restrict__ loT, const float* __restrict__ b1,
        const uint32_t* __restrict__ spk, float* __restrict__ I_all) {
    __shared__ __align__(16) char lds[53248];

    const int tid = threadIdx.x;
    const int l   = tid & 63;
    const int wv  = tid >> 6;
    const int t   = blockIdx.x >> 6;
    const int b0  = (blockIdx.x & 63) << 6;
    const int m0  = blockIdx.x << 6;

    f32x4 acc[4][4] = {};

    // fragment read addressing (shared swizzle sig for A and B)
    const int q   = l >> 4;
    const int sig = q ^ (l & 3) ^ ((l >> 2) & 3);
    const int a_base = LDS_A + ((l & 15) << 6) + (sig << 4);
    const int b_off  = (((wv << 6) + (l & 15)) << 6) + (sig << 4);

    // A-expansion thread mapping: row er, byte-group eq
    const int er = tid >> 2;
    const int eq = tid & 3;
    const int ea = LDS_A + (er << 6) + ((eq ^ (er & 3) ^ ((er >> 2) & 3)) << 4);
    const uint32_t* wptr = spk + (size_t)t * BATCH + b0 + er;

    for (int kw = 0; kw < KWORDS; ++kw) {
        __syncthreads();   // previous compute done with LDS

        // --- stage Bhi/Bmid/Blo chunk (k in [kw*32,kw*32+32), all 256 n) ---
#pragma unroll
        for (int i = 0; i < 4; ++i) {
            int s  = (wv << 8) + (i << 6) + l;          // slot 0..1023
            int n  = s >> 2;
            int qs = s & 3;
            int qd = qs ^ (n & 3) ^ ((n >> 2) & 3);     // swizzled data quarter
            size_t gb = (size_t)n * (KPAD * 2) + ((size_t)kw << 6) + ((size_t)qd << 4);
            int ldst = ((wv << 8) + (i << 6)) << 4;
            __builtin_amdgcn_global_load_lds(
                (const __attribute__((address_space(1))) void*)((const char*)hiT + gb),
                (__attribute__((address_space(3))) void*)(lds + LDS_BH + ldst),
                16, 0, 0);
            __builtin_amdgcn_global_load_lds(
                (const __attribute__((address_space(1))) void*)((const char*)midT + gb),
                (__attribute__((address_space(3))) void*)(lds + LDS_BM + ldst),
                16, 0, 0);
            __builtin_amdgcn_global_load_lds(
                (const __attribute__((address_space(1))) void*)((const char*)loT + gb),
                (__attribute__((address_space(3))) void*)(lds + LDS_BL + ldst),
                16, 0, 0);
        }

        // --- expand spike bits -> bf16 A tile (64 rows x 32 k) ---
        {
            uint32_t w = wptr[(size_t)kw * NROWS];
            uint32_t byte = (w >> (eq << 3)) & 0xFFu;
            u32x4 v;
            v.x = ((byte &   1u) ? 0x3F80u : 0u) | ((byte &   2u) ? 0x3F800000u : 0u);
            v.y = ((byte &   4u) ? 0x3F80u : 0u) | ((byte &   8u) ? 0x3F800000u : 0u);
            v.z = ((byte &  16u) ? 0x3F80u : 0u) | ((byte &  32u) ? 0x3F800000u : 0u);
            v.w = ((byte &  64u) ? 0x3F80u : 0u) | ((byte & 128u) ? 0x3F800000u : 0u);
            *(u32x4*)(lds + ea) = v;
        }

        __syncthreads();   // A visible + global_load_lds drained

        // --- compute: 4 mtiles x 4 ntiles x (hi,mid,lo) = 48 MFMA ---
        bf16x8 af[4];
#pragma unroll
        for (int mt = 0; mt < 4; ++mt)
            af[mt] = *(const bf16x8*)(lds + a_base + (mt << 10));
#pragma unroll
        for (int nt = 0; nt < 4; ++nt) {
            bf16x8 bh = *(const bf16x8*)(lds + LDS_BH + b_off + (nt << 10));
            bf16x8 bm = *(const bf16x8*)(lds + LDS_BM + b_off + (nt << 10));
            bf16x8 bl = *(const bf16x8*)(lds + LDS_BL + b_off + (nt << 10));
#pragma unroll
            for (int mt = 0; mt < 4; ++mt) {
                acc[mt][nt] = __builtin_amdgcn_mfma_f32_16x16x32_bf16(af[mt], bh, acc[mt][nt], 0, 0, 0);
                acc[mt][nt] = __builtin_amdgcn_mfma_f32_16x16x32_bf16(af[mt], bm, acc[mt][nt], 0, 0, 0);
                acc[mt][nt] = __builtin_amdgcn_mfma_f32_16x16x32_bf16(af[mt], bl, acc[mt][nt], 0, 0, 0);
            }
        }
    }

    // --- epilogue: acc -> I_all (+ b1) ---
    const int c0 = l & 15;
    float b1v[4];
#pragma unroll
    for (int nt = 0; nt < 4; ++nt)
        b1v[nt] = b1[(wv << 6) + (nt << 4) + c0];
#pragma unroll
    for (int mt = 0; mt < 4; ++mt) {
#pragma unroll
        for (int nt = 0; nt < 4; ++nt) {
            int col = (wv << 6) + (nt << 4) + c0;
#pragma unroll
            for (int r = 0; r < 4; ++r) {
                int row = m0 + (mt << 4) + (q << 2) + r;
                I_all[(size_t)row * HID + col] = acc[mt][nt][r] + b1v[nt];
            }
        }
    }
}

// ---------------------------------------------------------------------------
// Kernel C: LIF scan over t per (b,h); g[b,h] = sum_t 2^(t-10)*spk_t.
// ---------------------------------------------------------------------------
__global__ __launch_bounds__(256) void scan_k(
        const float* __restrict__ I_all, float* __restrict__ g) {
    int b = blockIdx.x;
    int h = threadIdx.x;
    const float* p = I_all + ((size_t)b << 8) + h;
    float v = 0.f, ga = 0.f, wt = 0.0009765625f;   // 2^-10
#pragma unroll
    for (int t = 0; t < T_STEPS; ++t) {
        float I = p[(size_t)t * BATCH * HID];
        v = v + (I - v) * 0.5f;
        if (v >= 1.0f) { ga += wt; v = 0.f; }
        wt += wt;
    }
    g[(b << 8) + h] = ga;
}

// ---------------------------------------------------------------------------
// Kernel D: out[b][c] = sum_h g[b][h]*Wr[h][c] + br[c]*(1 - 2^-10).
// ---------------------------------------------------------------------------
__global__ __launch_bounds__(256) void out_k(
        const float* __restrict__ g, const float* __restrict__ Wr,
        const float* __restrict__ br, float* __restrict__ out) {
    __shared__ float gl[4 * 256];
    int tid = threadIdx.x;
    int b0 = blockIdx.x << 2;
    *(float4*)&gl[tid << 2] = *(const float4*)&g[(b0 << 8) + (tid << 2)];
    __syncthreads();
    int row = tid >> 6;
    int c = tid & 63;
    if (c >= NCLS) return;
    const float* grow = &gl[row << 8];
    float acc = 0.f;
#pragma unroll 4
    for (int h = 0; h < HID; ++h)
        acc = fmaf(grow[h], Wr[h * NCLS + c], acc);
    out[(b0 + row) * NCLS + c] = acc + br[c] * 0.9990234375f;
}

extern "C" void kernel_launch(void* const* d_in, const int* in_sizes, int n_in,
                              void* d_out, int out_size, void* d_ws, size_t ws_size,
                              hipStream_t stream) {
    const float* x  = (const float*)d_in[0];
    const float* W1 = (const float*)d_in[1];
    const float* b1 = (const float*)d_in[2];
    const float* Wr = (const float*)d_in[3];
    const float* br = (const float*)d_in[4];
    float* out = (float*)d_out;

    float*    I_all = (float*)   ((char*)d_ws + WS_IALL_OFF);
    uint32_t* spk   = (uint32_t*)((char*)d_ws + WS_SPK_OFF);
    float*    g     = (float*)   ((char*)d_ws + WS_G_OFF);
    ushort*   w1hi  = (ushort*)  ((char*)d_ws + WS_W1HI_OFF);
    ushort*   w1md  = (ushort*)  ((char*)d_ws + WS_W1MD_OFF);
    ushort*   w1lo  = (ushort*)  ((char*)d_ws + WS_W1LO_OFF);

    splitk_k<<<HID, 256, 0, stream>>>(W1, w1hi, w1md, w1lo);
    spikegen_k<<<25 * 5 * 16, 256, 0, stream>>>(x, spk);
    gemm_mfma_k<<<NROWS / 64, 256, 0, stream>>>(w1hi, w1md, w1lo, b1, spk, I_all);
    scan_k<<<BATCH, 256, 0, stream>>>(I_all, g);
    out_k<<<BATCH / 4, 256, 0, stream>>>(g, Wr, br, out);
}

// Round 5
// 222.616 us; speedup vs baseline: 3.0275x; 1.0539x over previous
//
#include <hip/hip_runtime.h>
#include <stdint.h>

// ---------------------------------------------------------------------------
// SNN EMNIST forward: T=10, B=4096, IN=784, HID=256, NCLS=47
// spikegen (threefry) -> split W1 (EXACT 3-way bf16) -> MFMA gemm -> scan -> out
// ---------------------------------------------------------------------------

#define T_STEPS 10
#define BATCH   4096
#define IN_DIM  784
#define HID     256
#define NCLS    47
#define NROWS   (T_STEPS * BATCH)        // 40960
#define KWORDS  25                       // ceil(784/32)
#define KPAD    800                      // 25*32

// d_ws layout (bytes):
//   [0, 41943040)          I_all  : float [40960][256]
//   [41943040, 46039040)   spk    : u32   [25][10][4096]
//   [46039040, 50233344)   g      : float [4096][256]
//   W1{hi,mid,lo}T (bf16 [256][800], 409600 B each) OVERLAP the g region:
//   dead once gemm finishes; scan_k overwrites with g.
#define WS_IALL_OFF 0u
#define WS_SPK_OFF  41943040u
#define WS_G_OFF    46039040u
#define WS_W1HI_OFF WS_G_OFF
#define WS_W1MD_OFF (WS_G_OFF + 409600u)
#define WS_W1LO_OFF (WS_G_OFF + 819200u)

typedef __attribute__((ext_vector_type(8))) short    bf16x8;
typedef __attribute__((ext_vector_type(4))) float    f32x4;
typedef __attribute__((ext_vector_type(4))) uint32_t u32x4;

// Force v_alignbit_b32: plain (x<<r)|(x>>(32-r)) was NOT pattern-matched
// (R3/R4 VALU issue-time matches a 3-op rotate).
__device__ __forceinline__ uint32_t rotl32(uint32_t x, uint32_t r) {
    return __builtin_rotateleft32(x, r);
}

// JAX threefry2x32, key=(0,42), partitionable scheme: out = o0^o1, x0=0, x1=i.
__device__ __forceinline__ uint32_t tf_hash(uint32_t lo) {
    const uint32_t ks0 = 0u;
    const uint32_t ks1 = 42u;
    const uint32_t ks2 = 0x1BD11BDAu ^ 0u ^ 42u;
    uint32_t x0 = 0u + ks0;
    uint32_t x1 = lo + ks1;
#define TF_RND(r) { x0 += x1; x1 = rotl32(x1, r); x1 ^= x0; }
    TF_RND(13) TF_RND(15) TF_RND(26) TF_RND(6)
    x0 += ks1; x1 += ks2 + 1u;
    TF_RND(17) TF_RND(29) TF_RND(16) TF_RND(24)
    x0 += ks2; x1 += ks0 + 2u;
    TF_RND(13) TF_RND(15) TF_RND(26) TF_RND(6)
    x0 += ks0; x1 += ks1 + 3u;
    TF_RND(17) TF_RND(29) TF_RND(16) TF_RND(24)
    x0 += ks1; x1 += ks2 + 4u;
    TF_RND(13) TF_RND(15) TF_RND(26) TF_RND(6)
    x0 += ks2; x1 += ks0 + 5u;
#undef TF_RND
    return x0 ^ x1;
}

// ---------------------------------------------------------------------------
// Kernel A: spike generation -> bit-packed words spk[(kw*10+t)*4096 + b].
// Thread = (kw, tg, b): tg covers t = {2tg, 2tg+1}. Grid = 2000 blocks.
// ---------------------------------------------------------------------------
__global__ __launch_bounds__(256) void spikegen_k(
        const float* __restrict__ x, uint32_t* __restrict__ spk) {
    const int bid = blockIdx.x;          // (kw*5 + tg)*16 + bblk
    const int kw  = bid / 80;
    const int rem = bid - kw * 80;
    const int tg  = rem >> 4;
    const int b   = ((rem & 15) << 8) + threadIdx.x;
    const int t0  = tg << 1;
    const int kbase = kw << 5;

    const uint32_t tstep = (uint32_t)(BATCH * IN_DIM);
    const uint32_t ibase0 = (uint32_t)(b * IN_DIM + kbase) + (uint32_t)t0 * tstep;

    uint32_t w0 = 0u, w1 = 0u;
    const int ng = (kw == 24) ? 4 : 8;   // float4 groups (wave-uniform branch)

    for (int g4 = 0; g4 < ng; ++g4) {
        float4 xv = *(const float4*)&x[b * IN_DIM + kbase + (g4 << 2)];
        float Xs[4] = {xv.x * 8388608.0f, xv.y * 8388608.0f,
                       xv.z * 8388608.0f, xv.w * 8388608.0f};
#pragma unroll
        for (int j = 0; j < 4; ++j) {
            int kk = (g4 << 2) + j;
            uint32_t i0 = ibase0 + (uint32_t)kk;
            uint32_t h0 = tf_hash(i0);
            uint32_t h1 = tf_hash(i0 + tstep);
            if ((float)(h0 >> 9) < Xs[j]) w0 |= (1u << kk);
            if ((float)(h1 >> 9) < Xs[j]) w1 |= (1u << kk);
        }
    }
    spk[(kw * T_STEPS + t0    ) * BATCH + b] = w0;
    spk[(kw * T_STEPS + t0 + 1) * BATCH + b] = w1;
}

// ---------------------------------------------------------------------------
// Kernel B0: split W1 (f32 [784][256]) into transposed bf16 hi/mid/lo
// [256][800]. EXACT: hi+mid+lo == w bitwise.
// ---------------------------------------------------------------------------
__global__ __launch_bounds__(256) void splitk_k(
        const float* __restrict__ W1, ushort* __restrict__ hiT,
        ushort* __restrict__ midT, ushort* __restrict__ loT) {
    int n = blockIdx.x;                  // 0..255
    for (int k = threadIdx.x; k < KPAD; k += 256) {
        float w = (k < IN_DIM) ? W1[k * HID + n] : 0.0f;
        uint32_t u = __float_as_uint(w);
        uint32_t hb = (u + 0x7FFFu + ((u >> 16) & 1u)) >> 16;    // RNE to bf16
        float hf = __uint_as_float(hb << 16);
        float r1 = w - hf;                                       // exact
        uint32_t u1 = __float_as_uint(r1);
        uint32_t mb = (u1 + 0x7FFFu + ((u1 >> 16) & 1u)) >> 16;  // RNE
        float mf2 = __uint_as_float(mb << 16);
        float r2 = r1 - mf2;                                     // exact
        uint32_t u2 = __float_as_uint(r2);
        uint32_t lb = (u2 + 0x7FFFu + ((u2 >> 16) & 1u)) >> 16;  // exact fit
        hiT [n * KPAD + k] = (ushort)hb;
        midT[n * KPAD + k] = (ushort)mb;
        loT [n * KPAD + k] = (ushort)lb;
    }
}

// ---------------------------------------------------------------------------
// Kernel B: I_all = spikes @ W1 + b1 via bf16 MFMA (hi+mid+lo exact split).
// Block: 64 rows (one t, 64 b) x 128 cols, 4 waves; wave = 64 rows x 32 cols
// = 4x2 tiles of 16x16x32. Grid = 10*64*2 = 1280 = exactly 5 blocks/CU
// (R4's 640-block/256-col tile ran at 19% occupancy, grid-starved).
// LDS: A 4KB + Bhi/Bmid/Blo 8KB each = 28KB -> 5 blocks/CU resident.
// XOR-swizzled 16B quarters keep every ds_read_b128 <=2-way (free).
// Same K order & plane order as R4 -> bitwise-identical I_all.
// ---------------------------------------------------------------------------
#define LDS_A  0
#define LDS_BH 4096
#define LDS_BM 12288
#define LDS_BL 20480

__global__ __launch_bounds__(256, 5) void gemm_mfma_k(
        const ushort* __restrict__ hiT, const ushort* __restrict__ midT,
        const ushort* __restrict__ loT, const float* __restrict__ b1,
        const uint32_t* __restrict__ spk, float* __restrict__ I_all) {
    __shared__ __align__(16) char lds[28672];

    const int tid = threadIdx.x;
    const int l   = tid & 63;
    const int wv  = tid >> 6;
    const int bid = blockIdx.x;
    const int t    = bid >> 7;           // 128 blocks per t
    const int rem  = bid & 127;
    const int b0   = (rem >> 1) << 6;
    const int nc0  = (rem & 1) << 7;     // col offset 0 or 128
    const int m0   = (t << 12) + b0;

    f32x4 acc[4][2] = {};

    // fragment read addressing (shared swizzle sig for A and B)
    const int q   = l >> 4;
    const int sig = q ^ (l & 3) ^ ((l >> 2) & 3);
    const int a_base = LDS_A + ((l & 15) << 6) + (sig << 4);
    const int b_base = (((wv << 5) + (l & 15)) << 6) + (sig << 4);

    // A-expansion thread mapping: row er, byte-group eq
    const int er = tid >> 2;
    const int eq = tid & 3;
    const int ea = LDS_A + (er << 6) + ((eq ^ (er & 3) ^ ((er >> 2) & 3)) << 4);
    const uint32_t* wptr = spk + (size_t)t * BATCH + b0 + er;

    for (int kw = 0; kw < KWORDS; ++kw) {
        __syncthreads();   // previous compute done with LDS

        // --- stage Bhi/Bmid/Blo chunk (k in [kw*32,kw*32+32), 128 n) ---
#pragma unroll
        for (int i = 0; i < 2; ++i) {
            int s  = (i << 8) + tid;                    // slot 0..511
            int n  = s >> 2;
            int qs = s & 3;
            int qd = qs ^ (n & 3) ^ ((n >> 2) & 3);     // swizzled data quarter
            size_t gb = (size_t)(nc0 + n) * (KPAD * 2) + ((size_t)kw << 6) + ((size_t)qd << 4);
            int ldst = s << 4;
            __builtin_amdgcn_global_load_lds(
                (const __attribute__((address_space(1))) void*)((const char*)hiT + gb),
                (__attribute__((address_space(3))) void*)(lds + LDS_BH + ldst),
                16, 0, 0);
            __builtin_amdgcn_global_load_lds(
                (const __attribute__((address_space(1))) void*)((const char*)midT + gb),
                (__attribute__((address_space(3))) void*)(lds + LDS_BM + ldst),
                16, 0, 0);
            __builtin_amdgcn_global_load_lds(
                (const __attribute__((address_space(1))) void*)((const char*)loT + gb),
                (__attribute__((address_space(3))) void*)(lds + LDS_BL + ldst),
                16, 0, 0);
        }

        // --- expand spike bits -> bf16 A tile (64 rows x 32 k) ---
        {
            uint32_t w = wptr[(size_t)kw * NROWS];
            uint32_t byte = (w >> (eq << 3)) & 0xFFu;
            u32x4 v;
            v.x = ((byte &   1u) ? 0x3F80u : 0u) | ((byte &   2u) ? 0x3F800000u : 0u);
            v.y = ((byte &   4u) ? 0x3F80u : 0u) | ((byte &   8u) ? 0x3F800000u : 0u);
            v.z = ((byte &  16u) ? 0x3F80u : 0u) | ((byte &  32u) ? 0x3F800000u : 0u);
            v.w = ((byte &  64u) ? 0x3F80u : 0u) | ((byte & 128u) ? 0x3F800000u : 0u);
            *(u32x4*)(lds + ea) = v;
        }

        __syncthreads();   // A visible + global_load_lds drained

        // --- compute: 4 mtiles x 2 ntiles x (hi,mid,lo) = 24 MFMA ---
        bf16x8 af[4];
#pragma unroll
        for (int mt = 0; mt < 4; ++mt)
            af[mt] = *(const bf16x8*)(lds + a_base + (mt << 10));
#pragma unroll
        for (int nt = 0; nt < 2; ++nt) {
            bf16x8 bh = *(const bf16x8*)(lds + LDS_BH + b_base + (nt << 10));
            bf16x8 bm = *(const bf16x8*)(lds + LDS_BM + b_base + (nt << 10));
            bf16x8 bl = *(const bf16x8*)(lds + LDS_BL + b_base + (nt << 10));
#pragma unroll
            for (int mt = 0; mt < 4; ++mt) {
                acc[mt][nt] = __builtin_amdgcn_mfma_f32_16x16x32_bf16(af[mt], bh, acc[mt][nt], 0, 0, 0);
                acc[mt][nt] = __builtin_amdgcn_mfma_f32_16x16x32_bf16(af[mt], bm, acc[mt][nt], 0, 0, 0);
                acc[mt][nt] = __builtin_amdgcn_mfma_f32_16x16x32_bf16(af[mt], bl, acc[mt][nt], 0, 0, 0);
            }
        }
    }

    // --- epilogue: acc -> I_all (+ b1) ---
    const int c0 = l & 15;
    float b1v[2];
#pragma unroll
    for (int nt = 0; nt < 2; ++nt)
        b1v[nt] = b1[nc0 + (wv << 5) + (nt << 4) + c0];
#pragma unroll
    for (int mt = 0; mt < 4; ++mt) {
#pragma unroll
        for (int nt = 0; nt < 2; ++nt) {
            int col = nc0 + (wv << 5) + (nt << 4) + c0;
#pragma unroll
            for (int r = 0; r < 4; ++r) {
                int row = m0 + (mt << 4) + (q << 2) + r;
                I_all[(size_t)row * HID + col] = acc[mt][nt][r] + b1v[nt];
            }
        }
    }
}

// ---------------------------------------------------------------------------
// Kernel C: LIF scan over t per (b,h); g[b,h] = sum_t 2^(t-10)*spk_t.
// ---------------------------------------------------------------------------
__global__ __launch_bounds__(256) void scan_k(
        const float* __restrict__ I_all, float* __restrict__ g) {
    int b = blockIdx.x;
    int h = threadIdx.x;
    const float* p = I_all + ((size_t)b << 8) + h;
    float v = 0.f, ga = 0.f, wt = 0.0009765625f;   // 2^-10
#pragma unroll
    for (int t = 0; t < T_STEPS; ++t) {
        float I = p[(size_t)t * BATCH * HID];
        v = v + (I - v) * 0.5f;
        if (v >= 1.0f) { ga += wt; v = 0.f; }
        wt += wt;
    }
    g[(b << 8) + h] = ga;
}

// ---------------------------------------------------------------------------
// Kernel D: out[b][c] = sum_h g[b][h]*Wr[h][c] + br[c]*(1 - 2^-10).
// ---------------------------------------------------------------------------
__global__ __launch_bounds__(256) void out_k(
        const float* __restrict__ g, const float* __restrict__ Wr,
        const float* __restrict__ br, float* __restrict__ out) {
    __shared__ float gl[4 * 256];
    int tid = threadIdx.x;
    int b0 = blockIdx.x << 2;
    *(float4*)&gl[tid << 2] = *(const float4*)&g[(b0 << 8) + (tid << 2)];
    __syncthreads();
    int row = tid >> 6;
    int c = tid & 63;
    if (c >= NCLS) return;
    const float* grow = &gl[row << 8];
    float acc = 0.f;
#pragma unroll 4
    for (int h = 0; h < HID; ++h)
        acc = fmaf(grow[h], Wr[h * NCLS + c], acc);
    out[(b0 + row) * NCLS + c] = acc + br[c] * 0.9990234375f;
}

extern "C" void kernel_launch(void* const* d_in, const int* in_sizes, int n_in,
                              void* d_out, int out_size, void* d_ws, size_t ws_size,
                              hipStream_t stream) {
    const float* x  = (const float*)d_in[0];
    const float* W1 = (const float*)d_in[1];
    const float* b1 = (const float*)d_in[2];
    const float* Wr = (const float*)d_in[3];
    const float* br = (const float*)d_in[4];
    float* out = (float*)d_out;

    float*    I_all = (float*)   ((char*)d_ws + WS_IALL_OFF);
    uint32_t* spk   = (uint32_t*)((char*)d_ws + WS_SPK_OFF);
    float*    g     = (float*)   ((char*)d_ws + WS_G_OFF);
    ushort*   w1hi  = (ushort*)  ((char*)d_ws + WS_W1HI_OFF);
    ushort*   w1md  = (ushort*)  ((char*)d_ws + WS_W1MD_OFF);
    ushort*   w1lo  = (ushort*)  ((char*)d_ws + WS_W1LO_OFF);

    splitk_k<<<HID, 256, 0, stream>>>(W1, w1hi, w1md, w1lo);
    spikegen_k<<<25 * 5 * 16, 256, 0, stream>>>(x, spk);
    gemm_mfma_k<<<1280, 256, 0, stream>>>(w1hi, w1md, w1lo, b1, spk, I_all);
    scan_k<<<BATCH, 256, 0, stream>>>(I_all, g);
    out_k<<<BATCH / 4, 256, 0, stream>>>(g, Wr, br, out);
}

// Round 6
// 209.672 us; speedup vs baseline: 3.2144x; 1.0617x over previous
//
#include <hip/hip_runtime.h>
#include <stdint.h>

// ---------------------------------------------------------------------------
// SNN EMNIST forward: T=10, B=4096, IN=784, HID=256, NCLS=47
// splitk (EXACT 3-way bf16 W1) -> fused spikegen+MFMA gemm -> LIF scan -> out
// Spikes are generated INLINE in the gemm K-loop (thread (row,byte) hashes
// its 8 bits directly) — the hash VALU work overlaps the MFMA pipe across
// the block's waves instead of running as a separate serial dispatch.
// ---------------------------------------------------------------------------

#define T_STEPS 10
#define BATCH   4096
#define IN_DIM  784
#define HID     256
#define NCLS    47
#define NROWS   (T_STEPS * BATCH)        // 40960
#define KWORDS  25                       // ceil(784/32)
#define KPAD    800                      // 25*32

// d_ws layout (bytes):
//   [0, 41943040)          I_all  : float [40960][256]
//   [46039040, 50233344)   g      : float [4096][256]
//   W1{hi,mid,lo}T (bf16 [256][800], 409600 B each) OVERLAP the g region:
//   dead once gemm finishes; scan_k overwrites with g.
#define WS_IALL_OFF 0u
#define WS_G_OFF    46039040u
#define WS_W1HI_OFF WS_G_OFF
#define WS_W1MD_OFF (WS_G_OFF + 409600u)
#define WS_W1LO_OFF (WS_G_OFF + 819200u)

typedef __attribute__((ext_vector_type(8))) short    bf16x8;
typedef __attribute__((ext_vector_type(4))) float    f32x4;
typedef __attribute__((ext_vector_type(4))) uint32_t u32x4;

// Single-instruction rotate: v_alignbit_b32 (x:x) >> (32-r) == rotl(x,r).
// (R5 showed neither (x<<r)|(x>>(32-r)) nor __builtin_rotateleft32 got
// pattern-matched — VALU issue time sat at the 3-op-rotate floor.)
__device__ __forceinline__ uint32_t rotl32(uint32_t x, uint32_t r) {
    return __builtin_amdgcn_alignbit(x, x, 32u - r);
}

// JAX threefry2x32, key=(0,42), partitionable scheme: out = o0^o1, x0=0, x1=i.
__device__ __forceinline__ uint32_t tf_hash(uint32_t lo) {
    const uint32_t ks0 = 0u;
    const uint32_t ks1 = 42u;
    const uint32_t ks2 = 0x1BD11BDAu ^ 0u ^ 42u;
    uint32_t x0 = 0u + ks0;
    uint32_t x1 = lo + ks1;
#define TF_RND(r) { x0 += x1; x1 = rotl32(x1, r); x1 ^= x0; }
    TF_RND(13) TF_RND(15) TF_RND(26) TF_RND(6)
    x0 += ks1; x1 += ks2 + 1u;
    TF_RND(17) TF_RND(29) TF_RND(16) TF_RND(24)
    x0 += ks2; x1 += ks0 + 2u;
    TF_RND(13) TF_RND(15) TF_RND(26) TF_RND(6)
    x0 += ks0; x1 += ks1 + 3u;
    TF_RND(17) TF_RND(29) TF_RND(16) TF_RND(24)
    x0 += ks1; x1 += ks2 + 4u;
    TF_RND(13) TF_RND(15) TF_RND(26) TF_RND(6)
    x0 += ks2; x1 += ks0 + 5u;
#undef TF_RND
    return x0 ^ x1;
}

// ---------------------------------------------------------------------------
// Kernel B0: split W1 (f32 [784][256]) into transposed bf16 hi/mid/lo
// [256][800]. EXACT: hi+mid+lo == w bitwise.
// ---------------------------------------------------------------------------
__global__ __launch_bounds__(256) void splitk_k(
        const float* __restrict__ W1, ushort* __restrict__ hiT,
        ushort* __restrict__ midT, ushort* __restrict__ loT) {
    int n = blockIdx.x;                  // 0..255
    for (int k = threadIdx.x; k < KPAD; k += 256) {
        float w = (k < IN_DIM) ? W1[k * HID + n] : 0.0f;
        uint32_t u = __float_as_uint(w);
        uint32_t hb = (u + 0x7FFFu + ((u >> 16) & 1u)) >> 16;    // RNE to bf16
        float hf = __uint_as_float(hb << 16);
        float r1 = w - hf;                                       // exact
        uint32_t u1 = __float_as_uint(r1);
        uint32_t mb = (u1 + 0x7FFFu + ((u1 >> 16) & 1u)) >> 16;  // RNE
        float mf2 = __uint_as_float(mb << 16);
        float r2 = r1 - mf2;                                     // exact
        uint32_t u2 = __float_as_uint(r2);
        uint32_t lb = (u2 + 0x7FFFu + ((u2 >> 16) & 1u)) >> 16;  // exact fit
        hiT [n * KPAD + k] = (ushort)hb;
        midT[n * KPAD + k] = (ushort)mb;
        loT [n * KPAD + k] = (ushort)lb;
    }
}

// ---------------------------------------------------------------------------
// Fused spikegen + GEMM: I_all = bernoulli(x) @ W1 + b1.
// Block: 64 rows (one t, 64 b) x 256 cols, 4 waves; wave = 64x64 = 4x4 tiles
// of 16x16x32. K-loop over 25 K-slabs of 32. Per iter, thread (er=tid>>2,
// eq=tid&3) hashes its 8 spike bits (row b0+er, k=kw*32+eq*8..+7) and writes
// the bf16 A-fragment to LDS; B hi/mid/lo staged via global_load_lds w=16.
// XOR-swizzled 16B quarters keep every ds_read_b128 <=2-way (free).
// Accumulation order identical to R4/R5 -> bitwise-identical I_all.
// ---------------------------------------------------------------------------
#define LDS_A  0
#define LDS_BH 4096
#define LDS_BM 20480
#define LDS_BL 36864

__global__ __launch_bounds__(256, 3) void fused_gemm_k(
        const ushort* __restrict__ hiT, const ushort* __restrict__ midT,
        const ushort* __restrict__ loT, const float* __restrict__ b1,
        const float* __restrict__ x, float* __restrict__ I_all) {
    __shared__ __align__(16) char lds[53248];

    const int tid = threadIdx.x;
    const int l   = tid & 63;
    const int wv  = tid >> 6;
    const int t   = blockIdx.x >> 6;     // 64 blocks per timestep
    const int b0  = (blockIdx.x & 63) << 6;
    const int m0  = blockIdx.x << 6;

    f32x4 acc[4][4] = {};

    // fragment read addressing (shared swizzle sig for A and B)
    const int q   = l >> 4;
    const int sig = q ^ (l & 3) ^ ((l >> 2) & 3);
    const int a_base = LDS_A + ((l & 15) << 6) + (sig << 4);
    const int b_off  = (((wv << 6) + (l & 15)) << 6) + (sig << 4);

    // A-expansion thread mapping: row er (0..63), byte-group eq (0..3)
    const int er = tid >> 2;
    const int eq = tid & 3;
    const int ea = LDS_A + (er << 6) + ((eq ^ (er & 3) ^ ((er >> 2) & 3)) << 4);
    const int row_b = b0 + er;
    const float* xrow = x + (size_t)row_b * IN_DIM;
    const uint32_t ibase = (uint32_t)(row_b * IN_DIM)
                         + (uint32_t)t * (uint32_t)(BATCH * IN_DIM);

    for (int kw = 0; kw < KWORDS; ++kw) {
        __syncthreads();   // previous compute done with LDS

        // --- stage Bhi/Bmid/Blo K-slab (k in [kw*32,kw*32+32), 256 n) ---
#pragma unroll
        for (int i = 0; i < 4; ++i) {
            int s  = (wv << 8) + (i << 6) + l;          // slot 0..1023
            int n  = s >> 2;
            int qs = s & 3;
            int qd = qs ^ (n & 3) ^ ((n >> 2) & 3);     // swizzled data quarter
            size_t gb = (size_t)n * (KPAD * 2) + ((size_t)kw << 6) + ((size_t)qd << 4);
            int ldst = ((wv << 8) + (i << 6)) << 4;
            __builtin_amdgcn_global_load_lds(
                (const __attribute__((address_space(1))) void*)((const char*)hiT + gb),
                (__attribute__((address_space(3))) void*)(lds + LDS_BH + ldst),
                16, 0, 0);
            __builtin_amdgcn_global_load_lds(
                (const __attribute__((address_space(1))) void*)((const char*)midT + gb),
                (__attribute__((address_space(3))) void*)(lds + LDS_BM + ldst),
                16, 0, 0);
            __builtin_amdgcn_global_load_lds(
                (const __attribute__((address_space(1))) void*)((const char*)loT + gb),
                (__attribute__((address_space(3))) void*)(lds + LDS_BL + ldst),
                16, 0, 0);
        }

        // --- inline spikegen: hash 8 bits -> bf16 A fragment (16 B) ---
        {
            u32x4 v = {0u, 0u, 0u, 0u};
            // kw==24: k>=784 doesn't exist for eq>=2 -> keep zeros (also
            // guards the x OOB read on the last batch row).
            if (!(kw == 24 && eq >= 2)) {
                const int k0 = (kw << 5) + (eq << 3);
                float4 xa = *(const float4*)&xrow[k0];
                float4 xb = *(const float4*)&xrow[k0 + 4];
                const uint32_t ib = ibase + (uint32_t)k0;
                uint32_t c0 = ((float)(tf_hash(ib + 0u) >> 9) < xa.x * 8388608.0f) ? 0x3F80u : 0u;
                uint32_t c1 = ((float)(tf_hash(ib + 1u) >> 9) < xa.y * 8388608.0f) ? 0x3F800000u : 0u;
                uint32_t c2 = ((float)(tf_hash(ib + 2u) >> 9) < xa.z * 8388608.0f) ? 0x3F80u : 0u;
                uint32_t c3 = ((float)(tf_hash(ib + 3u) >> 9) < xa.w * 8388608.0f) ? 0x3F800000u : 0u;
                uint32_t c4 = ((float)(tf_hash(ib + 4u) >> 9) < xb.x * 8388608.0f) ? 0x3F80u : 0u;
                uint32_t c5 = ((float)(tf_hash(ib + 5u) >> 9) < xb.y * 8388608.0f) ? 0x3F800000u : 0u;
                uint32_t c6 = ((float)(tf_hash(ib + 6u) >> 9) < xb.z * 8388608.0f) ? 0x3F80u : 0u;
                uint32_t c7 = ((float)(tf_hash(ib + 7u) >> 9) < xb.w * 8388608.0f) ? 0x3F800000u : 0u;
                v.x = c0 | c1;  v.y = c2 | c3;  v.z = c4 | c5;  v.w = c6 | c7;
            }
            *(u32x4*)(lds + ea) = v;     // always store (zeros on tail)
        }

        __syncthreads();   // A visible + global_load_lds drained

        // --- compute: 4 mtiles x 4 ntiles x (hi,mid,lo) = 48 MFMA ---
        bf16x8 af[4];
#pragma unroll
        for (int mt = 0; mt < 4; ++mt)
            af[mt] = *(const bf16x8*)(lds + a_base + (mt << 10));
#pragma unroll
        for (int nt = 0; nt < 4; ++nt) {
            bf16x8 bh = *(const bf16x8*)(lds + LDS_BH + b_off + (nt << 10));
            bf16x8 bm = *(const bf16x8*)(lds + LDS_BM + b_off + (nt << 10));
            bf16x8 bl = *(const bf16x8*)(lds + LDS_BL + b_off + (nt << 10));
#pragma unroll
            for (int mt = 0; mt < 4; ++mt) {
                acc[mt][nt] = __builtin_amdgcn_mfma_f32_16x16x32_bf16(af[mt], bh, acc[mt][nt], 0, 0, 0);
                acc[mt][nt] = __builtin_amdgcn_mfma_f32_16x16x32_bf16(af[mt], bm, acc[mt][nt], 0, 0, 0);
                acc[mt][nt] = __builtin_amdgcn_mfma_f32_16x16x32_bf16(af[mt], bl, acc[mt][nt], 0, 0, 0);
            }
        }
    }

    // --- epilogue: acc -> I_all (+ b1) ---
    const int c0 = l & 15;
    float b1v[4];
#pragma unroll
    for (int nt = 0; nt < 4; ++nt)
        b1v[nt] = b1[(wv << 6) + (nt << 4) + c0];
#pragma unroll
    for (int mt = 0; mt < 4; ++mt) {
#pragma unroll
        for (int nt = 0; nt < 4; ++nt) {
            int col = (wv << 6) + (nt << 4) + c0;
#pragma unroll
            for (int r = 0; r < 4; ++r) {
                int row = m0 + (mt << 4) + (q << 2) + r;
                I_all[(size_t)row * HID + col] = acc[mt][nt][r] + b1v[nt];
            }
        }
    }
}

// ---------------------------------------------------------------------------
// Kernel C: LIF scan over t per (b,h); g[b,h] = sum_t 2^(t-10)*spk_t.
// ---------------------------------------------------------------------------
__global__ __launch_bounds__(256) void scan_k(
        const float* __restrict__ I_all, float* __restrict__ g) {
    int b = blockIdx.x;
    int h = threadIdx.x;
    const float* p = I_all + ((size_t)b << 8) + h;
    float v = 0.f, ga = 0.f, wt = 0.0009765625f;   // 2^-10
#pragma unroll
    for (int t = 0; t < T_STEPS; ++t) {
        float I = p[(size_t)t * BATCH * HID];
        v = v + (I - v) * 0.5f;
        if (v >= 1.0f) { ga += wt; v = 0.f; }
        wt += wt;
    }
    g[(b << 8) + h] = ga;
}

// ---------------------------------------------------------------------------
// Kernel D: out[b][c] = sum_h g[b][h]*Wr[h][c] + br[c]*(1 - 2^-10).
// ---------------------------------------------------------------------------
__global__ __launch_bounds__(256) void out_k(
        const float* __restrict__ g, const float* __restrict__ Wr,
        const float* __restrict__ br, float* __restrict__ out) {
    __shared__ float gl[4 * 256];
    int tid = threadIdx.x;
    int b0 = blockIdx.x << 2;
    *(float4*)&gl[tid << 2] = *(const float4*)&g[(b0 << 8) + (tid << 2)];
    __syncthreads();
    int row = tid >> 6;
    int c = tid & 63;
    if (c >= NCLS) return;
    const float* grow = &gl[row << 8];
    float acc = 0.f;
#pragma unroll 4
    for (int h = 0; h < HID; ++h)
        acc = fmaf(grow[h], Wr[h * NCLS + c], acc);
    out[(b0 + row) * NCLS + c] = acc + br[c] * 0.9990234375f;
}

extern "C" void kernel_launch(void* const* d_in, const int* in_sizes, int n_in,
                              void* d_out, int out_size, void* d_ws, size_t ws_size,
                              hipStream_t stream) {
    const float* x  = (const float*)d_in[0];
    const float* W1 = (const float*)d_in[1];
    const float* b1 = (const float*)d_in[2];
    const float* Wr = (const float*)d_in[3];
    const float* br = (const float*)d_in[4];
    float* out = (float*)d_out;

    float*    I_all = (float*)   ((char*)d_ws + WS_IALL_OFF);
    float*    g     = (float*)   ((char*)d_ws + WS_G_OFF);
    ushort*   w1hi  = (ushort*)  ((char*)d_ws + WS_W1HI_OFF);
    ushort*   w1md  = (ushort*)  ((char*)d_ws + WS_W1MD_OFF);
    ushort*   w1lo  = (ushort*)  ((char*)d_ws + WS_W1LO_OFF);

    splitk_k<<<HID, 256, 0, stream>>>(W1, w1hi, w1md, w1lo);
    fused_gemm_k<<<NROWS / 64, 256, 0, stream>>>(w1hi, w1md, w1lo, b1, x, I_all);
    scan_k<<<BATCH, 256, 0, stream>>>(I_all, g);
    out_k<<<BATCH / 4, 256, 0, stream>>>(g, Wr, br, out);
}